// Round 15
// baseline (148.198 us; speedup 1.0000x reference)
//
#include <hip/hip_runtime.h>
#include <hip/hip_bf16.h>
#include <cstdint>

// Problem constants
#define BS     32
#define VARNUM 16384
#define EMB    128
#define SEEDD  128
#define NH     16
#define HALFV  8192

// Fused-kernel tiling
#define NCHUNK 32                  // blocks per batch
#define VT     (VARNUM / NCHUNK)   // 512 v per block
#define TV     64                  // v per tile
#define NTILE  (VT / TV)           // 8

// LDS strides (bytes)
#define EST 2080                   // E slab: [64 v][16 e] bf16 + 32B pad (R2/R8/R10-proven)
#define PST 144                    // p row stride: 72 bf16 (16h x 64v padded)

// Workspace layout (bytes)
#define OFF_NORMQ 0
#define SZ_NORMQ  (BS*NH*EMB*4)                  // 256 KB
#define OFF_LPART (OFF_NORMQ + SZ_NORMQ)
#define SZ_LPART  (BS*NCHUNK*NH*4)               // 64 KB
#define OFF_PACC  (OFF_LPART + SZ_LPART)
#define SZ_PACC   ((size_t)BS*NCHUNK*NH*EMB*4)   // 8.4 MB

typedef __attribute__((ext_vector_type(8))) short bf16x8;  // MFMA A/B frag (8 bf16)
typedef __attribute__((ext_vector_type(4))) float f32x4;   // MFMA C/D frag

// lgkm-only barrier: orders LDS producer/consumer WITHOUT draining vmcnt —
// prefetch global loads stay in flight across the barrier (T4 mechanism).
#define BAR() do { \
    asm volatile("s_waitcnt lgkmcnt(0)" ::: "memory"); \
    __builtin_amdgcn_s_barrier(); \
} while (0)

static __device__ __forceinline__ uint16_t f2bf(float f) {
    uint32_t u = __float_as_uint(f);
    return (uint16_t)((u + 0x7FFFu + ((u >> 16) & 1u)) >> 16);  // RTN-even
}
static __device__ __forceinline__ uint32_t packbf(float a, float b) {
    __hip_bfloat162 h = __float22bfloat162_rn(make_float2(a, b));  // v_cvt_pk_bf16_f32
    uint32_t u;
    __builtin_memcpy(&u, &h, 4);
    return u;
}
static __device__ __forceinline__ float dot4(float4 a, float4 b) {
    return a.x*b.x + a.y*b.y + a.z*b.z + a.w*b.w;
}

// K1: norm_qs[b,h,e] = normalize_e(tanh(sum_s w_qs[h,e,s]*seed[b,s]))
// 512 blocks (b,h) x 128 threads — parallelism matters here (R14 lesson).
__global__ __launch_bounds__(128) void k1_q(const float* __restrict__ seed,
                                            const float* __restrict__ wqs,
                                            float* __restrict__ normq) {
    const int bh = blockIdx.x;
    const int b = bh >> 4, h = bh & 15;
    const int e = threadIdx.x;
    __shared__ __align__(16) float s_seed[SEEDD];
    s_seed[e] = seed[b*SEEDD + e];
    __syncthreads();
    const float4* w4 = (const float4*)(wqs + ((size_t)(h*EMB + e))*SEEDD);
    const float4* s4 = (const float4*)s_seed;
    float acc = 0.f;
    #pragma unroll
    for (int j = 0; j < SEEDD/4; ++j) acc += dot4(w4[j], s4[j]);
    float t = tanhf(acc);
    float sq = t*t;
    #pragma unroll
    for (int off = 32; off; off >>= 1) sq += __shfl_xor(sq, off);
    __shared__ float s_part[2];
    if ((threadIdx.x & 63) == 0) s_part[threadIdx.x >> 6] = sq;
    __syncthreads();
    float tot = s_part[0] + s_part[1];
    normq[((size_t)b*NH + h)*EMB + e] = t * rsqrtf(tot);
}

// Fused (R10-proven, byte-identical): lane(llo,lhi) of wave w owns E row
// rr=w*16+llo, e-chunks f*32+lhi*8. QK A-frags straight from registers; E staged
// to LDS only for PV's B gather. One lgkm-only barrier per tile, E and P
// double-buffered; next tile's emb prefetched in regs across the BAR.
__global__ __launch_bounds__(256, 4) void k_fused(const float* __restrict__ emb,
                                                  const int* __restrict__ mask,
                                                  const float* __restrict__ normq,
                                                  float* __restrict__ pacc,
                                                  float* __restrict__ lpart) {
    const int chunk = blockIdx.x, b = blockIdx.y;
    const int tid = threadIdx.x;
    const int w   = tid >> 6;          // wave 0..3
    const int l   = tid & 63;
    const int lhi = l >> 4;            // 0..3
    const int llo = l & 15;            // 0..15
    const int rr  = w*16 + llo;        // this lane's tile row

    __shared__ __align__(16) unsigned char Elds[2][8*EST];  // 2 x 16640 B
    __shared__ __align__(16) unsigned char Plds[2][16*PST]; // 2 x 2304 B
    __shared__ __align__(16) float nsq[TV];                 // wave-private rows
    __shared__ float lred[4][NH];

    // ---- Q fragments in registers: B[k=e][n=h], lane: h=llo, k=f*32+lhi*8+i ----
    bf16x8 qf[4];
    {
        const float* qrow = normq + ((size_t)b*NH + llo)*EMB;
        #pragma unroll
        for (int f = 0; f < 4; ++f) {
            const float4* qs = (const float4*)(qrow + f*32 + lhi*8);
            float4 a = qs[0], c = qs[1];
            bf16x8 t;
            t[0]=(short)f2bf(a.x); t[1]=(short)f2bf(a.y); t[2]=(short)f2bf(a.z); t[3]=(short)f2bf(a.w);
            t[4]=(short)f2bf(c.x); t[5]=(short)f2bf(c.y); t[6]=(short)f2bf(c.z); t[7]=(short)f2bf(c.w);
            qf[f] = t;
        }
    }

    f32x4 acc0 = {0.f,0.f,0.f,0.f};   // O[h=lhi*4+r][e=w*32+llo]
    f32x4 acc1 = {0.f,0.f,0.f,0.f};   // O[h=lhi*4+r][e=w*32+16+llo]
    float Lh = 0.f;                   // partial sum_v p for h=llo

    const float* embB  = emb + (size_t)b*VARNUM*EMB;
    const int*   maskB = mask + b*HALFV;

    // ---- prologue: tile-0 mask + emb loads (lane-owned row, 4 e-chunks) ----
    int    mk;
    float4 pfa[4], pfb[4];
    {
        const int vg = chunk*VT + rr;
        mk = maskB[vg & (HALFV-1)];
        const float* rowp = embB + (size_t)(mk ? vg : (chunk*VT + w*16))*EMB;
        #pragma unroll
        for (int f = 0; f < 4; ++f) {
            const float4* src = (const float4*)(rowp + f*32 + lhi*8);
            pfa[f] = src[0]; pfb[f] = src[1];
        }
    }

    for (int t = 0; t < NTILE; ++t) {
        unsigned char* Ebuf = Elds[t & 1];
        unsigned char* Pbuf = Plds[t & 1];

        // next tile's mask (latency hidden under convert)
        int mkn = 0;
        if (t + 1 < NTILE)
            mkn = maskB[(chunk*VT + (t+1)*TV + rr) & (HALFV-1)];

        // ---- convert f32->bf16: QK frags in regs + E copy to LDS ----
        bf16x8 ef[4];
        float sq = 0.f;
        #pragma unroll
        for (int f = 0; f < 4; ++f) {
            float4 x0 = pfa[f], x1 = pfb[f];
            sq += dot4(x0,x0) + dot4(x1,x1);
            uint4 dd = make_uint4(packbf(x0.x,x0.y), packbf(x0.z,x0.w),
                                  packbf(x1.x,x1.y), packbf(x1.z,x1.w));
            *(uint4*)(Ebuf + (2*f + (lhi>>1))*EST + rr*32 + (lhi&1)*16) = dd;
            __builtin_memcpy(&ef[f], &dd, 16);
        }
        sq += __shfl_xor(sq, 16);
        sq += __shfl_xor(sq, 32);
        if (l < 16) nsq[w*16 + llo] = mk ? sq : 0.f;   // wave-private rows

        // ---- issue NEXT tile's emb loads (ride across the barrier) ----
        if (t + 1 < NTILE) {
            const int vg = chunk*VT + (t+1)*TV + rr;
            const float* rowp = embB + (size_t)(mkn ? vg : (chunk*VT + (t+1)*TV + w*16))*EMB;
            #pragma unroll
            for (int f = 0; f < 4; ++f) {
                const float4* src = (const float4*)(rowp + f*32 + lhi*8);
                pfa[f] = src[0]; pfb[f] = src[1];
            }
            mk = mkn;
        }

        // ---- QK from registers: S[v=w*16+..][h] ----
        f32x4 s = {0.f,0.f,0.f,0.f};
        #pragma unroll
        for (int f = 0; f < 4; ++f)
            s = __builtin_amdgcn_mfma_f32_16x16x32_bf16(ef[f], qf[f], s, 0, 0, 0);

        // lane holds S[v = w*16 + lhi*4 + r][h = llo]
        f32x4 nn = *(const f32x4*)(&nsq[w*16 + lhi*4]);   // within-wave dep only
        float p[4];
        #pragma unroll
        for (int r = 0; r < 4; ++r)
            p[r] = (nn[r] > 0.f) ? __expf(s[r]*rsqrtf(nn[r]) - 1.f) : 0.f;  // |cos|<=1
        uint32_t u0 = packbf(p[0], p[1]), u1 = packbf(p[2], p[3]);
        Lh += __uint_as_float(u0 << 16) + __uint_as_float(u0 & 0xFFFF0000u)
            + __uint_as_float(u1 << 16) + __uint_as_float(u1 & 0xFFFF0000u);
        {
            unsigned char* pdst = Pbuf + llo*PST + (w*16 + lhi*4)*2;
            *(uint32_t*)(pdst)     = u0;
            *(uint32_t*)(pdst + 4) = u1;
        }

        BAR();   // single barrier: E-writes + P-writes -> PV reads (dbuf guards rest)

        // ---- PV: O[h][e] += P · E  (A=P b128; B=E u16 gathers, proven) ----
        #pragma unroll
        for (int kf = 0; kf < 2; ++kf) {
            // A-frag: lane(llo,lhi) needs P[h=llo][v = kf*32 + lhi*8 + i]
            bf16x8 pa = *(const bf16x8*)(Pbuf + llo*PST + kf*64 + lhi*16);
            #pragma unroll
            for (int et = 0; et < 2; ++et) {
                const unsigned char* base = Ebuf + (2*w + et)*EST + llo*2;
                bf16x8 bb;
                #pragma unroll
                for (int i = 0; i < 8; ++i)
                    bb[i] = *(const short*)(base + (size_t)(kf*32 + lhi*8 + i)*32);
                if (et == 0) acc0 = __builtin_amdgcn_mfma_f32_16x16x32_bf16(pa, bb, acc0, 0, 0, 0);
                else         acc1 = __builtin_amdgcn_mfma_f32_16x16x32_bf16(pa, bb, acc1, 0, 0, 0);
            }
        }
        // no trailing barrier: next tile writes the OTHER E/P buffers
    }

    // ---- epilogue: partial O and partial lsum ----
    float* pout = pacc + (((size_t)b*NCHUNK + chunk)*NH)*EMB;
    #pragma unroll
    for (int r = 0; r < 4; ++r) {
        pout[(lhi*4 + r)*EMB + w*32 + llo]      = acc0[r];
        pout[(lhi*4 + r)*EMB + w*32 + 16 + llo] = acc1[r];
    }
    Lh += __shfl_xor(Lh, 16);
    Lh += __shfl_xor(Lh, 32);
    if (l < 16) lred[w][l] = Lh;
    BAR();
    if (tid < 16)
        lpart[((size_t)b*NCHUNK + chunk)*NH + tid] =
            lred[0][tid] + lred[1][tid] + lred[2][tid] + lred[3][tid];
}

// K6: rc[b,h,e] = sum_chunk pacc / sum_chunk lpart.
// Block 0 ALSO computes the orthogonality loss directly from normq (replaces k2):
// 128 threads x 2 (h,g)-pairs x 32 batches, reduced in-block.
__global__ __launch_bounds__(128) void k6_out(const float* __restrict__ pacc,
                                              const float* __restrict__ lpart,
                                              const float* __restrict__ normq,
                                              float* __restrict__ out) {
    const int bh = blockIdx.x;
    const int b = bh >> 4, h = bh & 15;
    const int e = threadIdx.x;
    float L = 0.f;
    #pragma unroll
    for (int c = 0; c < NCHUNK; ++c) L += lpart[((size_t)b*NCHUNK + c)*NH + h];
    float acc = 0.f;
    for (int k = 0; k < NCHUNK; ++k)
        acc += pacc[(((size_t)b*NCHUNK + k)*NH + h)*EMB + e];
    out[((size_t)b*NH + h)*EMB + e] = acc / L;

    if (bh == 0) {   // block-uniform branch: loss = sum_b sum_{h,g} (q̂h·q̂g - I)^2 / BS
        const int g  = threadIdx.x & 15;
        const int h0 = threadIdx.x >> 4;          // 0..7 -> handles h0 and h0+8
        float sq = 0.f;
        for (int bb = 0; bb < BS; ++bb) {
            const float* nq = normq + (size_t)bb*NH*EMB;
            const float4* qg = (const float4*)(nq + g*EMB);
            #pragma unroll
            for (int hh = 0; hh < 2; ++hh) {
                const int hx = h0 + hh*8;
                const float4* qh = (const float4*)(nq + hx*EMB);
                float d = 0.f;
                #pragma unroll
                for (int j = 0; j < EMB/4; ++j) d += dot4(qh[j], qg[j]);
                d -= (hx == g) ? 1.f : 0.f;
                sq += d*d;
            }
        }
        #pragma unroll
        for (int off = 32; off; off >>= 1) sq += __shfl_xor(sq, off);
        __shared__ float sp2[2];
        if ((threadIdx.x & 63) == 0) sp2[threadIdx.x >> 6] = sq;
        __syncthreads();
        if (threadIdx.x == 0) out[BS*NH*EMB] = (sp2[0] + sp2[1]) / (float)BS;
    }
}

extern "C" void kernel_launch(void* const* d_in, const int* in_sizes, int n_in,
                              void* d_out, int out_size, void* d_ws, size_t ws_size,
                              hipStream_t stream) {
    const float* seed = (const float*)d_in[0];
    const float* emb  = (const float*)d_in[1];
    const int*   mask = (const int*)d_in[2];
    const float* wqs  = (const float*)d_in[3];
    float* out = (float*)d_out;

    char* ws = (char*)d_ws;
    float* normq = (float*)(ws + OFF_NORMQ);
    float* lpart = (float*)(ws + OFF_LPART);
    float* pacc  = (float*)(ws + OFF_PACC);

    k1_q<<<BS*NH, 128, 0, stream>>>(seed, wqs, normq);
    k_fused<<<dim3(NCHUNK, BS), 256, 0, stream>>>(emb, mask, normq, pacc, lpart);
    k6_out<<<BS*NH, 128, 0, stream>>>(pacc, lpart, normq, out);
}

// Round 16
// 50.617 us; speedup vs baseline: 2.9279x; 2.9279x over previous
//
#include <hip/hip_runtime.h>
#include <hip/hip_bf16.h>
#include <cstdint>

// Problem constants
#define BS     32
#define VARNUM 16384
#define EMB    128
#define SEEDD  128
#define NH     16
#define HALFV  8192

// Fused-kernel tiling
#define NCHUNK 32                  // blocks per batch
#define VT     (VARNUM / NCHUNK)   // 512 v per block
#define TV     64                  // v per tile
#define NTILE  (VT / TV)           // 8

// LDS strides (bytes)
#define EST 2080                   // E slab: [64 v][16 e] bf16 + 32B pad (R2/R8/R10-proven)
#define PST 144                    // p row stride: 72 bf16 (16h x 64v padded)

// Workspace layout (bytes)
#define OFF_NORMQ 0
#define SZ_NORMQ  (BS*NH*EMB*4)                  // 256 KB
#define OFF_LOSSP (OFF_NORMQ + SZ_NORMQ)
#define SZ_LOSSP  256
#define OFF_LPART (OFF_LOSSP + SZ_LOSSP)
#define SZ_LPART  (BS*NCHUNK*NH*4)               // 64 KB
#define OFF_PACC  (OFF_LPART + SZ_LPART)
#define SZ_PACC   ((size_t)BS*NCHUNK*NH*EMB*4)   // 8.4 MB

typedef __attribute__((ext_vector_type(8))) short bf16x8;  // MFMA A/B frag (8 bf16)
typedef __attribute__((ext_vector_type(4))) float f32x4;   // MFMA C/D frag

// lgkm-only barrier: orders LDS producer/consumer WITHOUT draining vmcnt —
// prefetch global loads stay in flight across the barrier (T4 mechanism).
#define BAR() do { \
    asm volatile("s_waitcnt lgkmcnt(0)" ::: "memory"); \
    __builtin_amdgcn_s_barrier(); \
} while (0)

static __device__ __forceinline__ uint16_t f2bf(float f) {
    uint32_t u = __float_as_uint(f);
    return (uint16_t)((u + 0x7FFFu + ((u >> 16) & 1u)) >> 16);  // RTN-even
}
static __device__ __forceinline__ uint32_t packbf(float a, float b) {
    __hip_bfloat162 h = __float22bfloat162_rn(make_float2(a, b));  // v_cvt_pk_bf16_f32
    uint32_t u;
    __builtin_memcpy(&u, &h, 4);
    return u;
}
static __device__ __forceinline__ float dot4(float4 a, float4 b) {
    return a.x*b.x + a.y*b.y + a.z*b.z + a.w*b.w;
}

// K1: norm_qs[b,h,e] = normalize_e(tanh(sum_s w_qs[h,e,s]*seed[b,s]))
__global__ __launch_bounds__(128) void k1_q(const float* __restrict__ seed,
                                            const float* __restrict__ wqs,
                                            float* __restrict__ normq) {
    const int bh = blockIdx.x;
    const int b = bh >> 4, h = bh & 15;
    const int e = threadIdx.x;
    __shared__ __align__(16) float s_seed[SEEDD];
    s_seed[e] = seed[b*SEEDD + e];
    __syncthreads();
    const float4* w4 = (const float4*)(wqs + ((size_t)(h*EMB + e))*SEEDD);
    const float4* s4 = (const float4*)s_seed;
    float acc = 0.f;
    #pragma unroll
    for (int j = 0; j < SEEDD/4; ++j) acc += dot4(w4[j], s4[j]);
    float t = tanhf(acc);
    float sq = t*t;
    #pragma unroll
    for (int off = 32; off; off >>= 1) sq += __shfl_xor(sq, off);
    __shared__ float s_part[2];
    if ((threadIdx.x & 63) == 0) s_part[threadIdx.x >> 6] = sq;
    __syncthreads();
    float tot = s_part[0] + s_part[1];
    normq[((size_t)b*NH + h)*EMB + e] = t * rsqrtf(tot);
}

// K2: per-batch loss partial: sum_{h,g} (q̂h·q̂g - I)^2
__global__ __launch_bounds__(256) void k2_loss(const float* __restrict__ normq,
                                               float* __restrict__ lossp) {
    const int b = blockIdx.x;
    const int h = threadIdx.x >> 4, g = threadIdx.x & 15;
    const float4* qh = (const float4*)(normq + ((size_t)b*NH + h)*EMB);
    const float4* qg = (const float4*)(normq + ((size_t)b*NH + g)*EMB);
    float d = 0.f;
    #pragma unroll
    for (int j = 0; j < EMB/4; ++j) d += dot4(qh[j], qg[j]);
    d -= (h == g) ? 1.f : 0.f;
    float sq = d*d;
    #pragma unroll
    for (int off = 32; off; off >>= 1) sq += __shfl_xor(sq, off);
    __shared__ float sp[4];
    if ((threadIdx.x & 63) == 0) sp[threadIdx.x >> 6] = sq;
    __syncthreads();
    if (threadIdx.x == 0) lossp[b] = sp[0] + sp[1] + sp[2] + sp[3];
}

// Fused (R10-proven): lane(llo,lhi) of wave w owns E row rr=w*16+llo, e-chunks
// f*32+lhi*8. QK A-frags straight from registers; E staged to LDS only for PV's
// B gather. One lgkm-only barrier per tile, E and P double-buffered; next
// tile's emb prefetched in regs across the BAR.
__global__ __launch_bounds__(256, 4) void k_fused(const float* __restrict__ emb,
                                                  const int* __restrict__ mask,
                                                  const float* __restrict__ normq,
                                                  float* __restrict__ pacc,
                                                  float* __restrict__ lpart) {
    const int chunk = blockIdx.x, b = blockIdx.y;
    const int tid = threadIdx.x;
    const int w   = tid >> 6;          // wave 0..3
    const int l   = tid & 63;
    const int lhi = l >> 4;            // 0..3
    const int llo = l & 15;            // 0..15
    const int rr  = w*16 + llo;        // this lane's tile row

    __shared__ __align__(16) unsigned char Elds[2][8*EST];  // 2 x 16640 B
    __shared__ __align__(16) unsigned char Plds[2][16*PST]; // 2 x 2304 B
    __shared__ __align__(16) float nsq[TV];                 // wave-private rows
    __shared__ float lred[4][NH];

    // ---- Q fragments in registers: B[k=e][n=h], lane: h=llo, k=f*32+lhi*8+i ----
    bf16x8 qf[4];
    {
        const float* qrow = normq + ((size_t)b*NH + llo)*EMB;
        #pragma unroll
        for (int f = 0; f < 4; ++f) {
            const float4* qs = (const float4*)(qrow + f*32 + lhi*8);
            float4 a = qs[0], c = qs[1];
            bf16x8 t;
            t[0]=(short)f2bf(a.x); t[1]=(short)f2bf(a.y); t[2]=(short)f2bf(a.z); t[3]=(short)f2bf(a.w);
            t[4]=(short)f2bf(c.x); t[5]=(short)f2bf(c.y); t[6]=(short)f2bf(c.z); t[7]=(short)f2bf(c.w);
            qf[f] = t;
        }
    }

    f32x4 acc0 = {0.f,0.f,0.f,0.f};   // O[h=lhi*4+r][e=w*32+llo]
    f32x4 acc1 = {0.f,0.f,0.f,0.f};   // O[h=lhi*4+r][e=w*32+16+llo]
    float Lh = 0.f;                   // partial sum_v p for h=llo

    const float* embB  = emb + (size_t)b*VARNUM*EMB;
    const int*   maskB = mask + b*HALFV;

    // ---- prologue: tile-0 mask + emb loads (lane-owned row, 4 e-chunks) ----
    int    mk;
    float4 pfa[4], pfb[4];
    {
        const int vg = chunk*VT + rr;
        mk = maskB[vg & (HALFV-1)];
        const float* rowp = embB + (size_t)(mk ? vg : (chunk*VT + w*16))*EMB;
        #pragma unroll
        for (int f = 0; f < 4; ++f) {
            const float4* src = (const float4*)(rowp + f*32 + lhi*8);
            pfa[f] = src[0]; pfb[f] = src[1];
        }
    }

    for (int t = 0; t < NTILE; ++t) {
        unsigned char* Ebuf = Elds[t & 1];
        unsigned char* Pbuf = Plds[t & 1];

        // next tile's mask (latency hidden under convert)
        int mkn = 0;
        if (t + 1 < NTILE)
            mkn = maskB[(chunk*VT + (t+1)*TV + rr) & (HALFV-1)];

        // ---- convert f32->bf16: QK frags in regs + E copy to LDS ----
        bf16x8 ef[4];
        float sq = 0.f;
        #pragma unroll
        for (int f = 0; f < 4; ++f) {
            float4 x0 = pfa[f], x1 = pfb[f];
            sq += dot4(x0,x0) + dot4(x1,x1);
            uint4 dd = make_uint4(packbf(x0.x,x0.y), packbf(x0.z,x0.w),
                                  packbf(x1.x,x1.y), packbf(x1.z,x1.w));
            *(uint4*)(Ebuf + (2*f + (lhi>>1))*EST + rr*32 + (lhi&1)*16) = dd;
            __builtin_memcpy(&ef[f], &dd, 16);
        }
        sq += __shfl_xor(sq, 16);
        sq += __shfl_xor(sq, 32);
        if (l < 16) nsq[w*16 + llo] = mk ? sq : 0.f;   // wave-private rows

        // ---- issue NEXT tile's emb loads (ride across the barrier) ----
        if (t + 1 < NTILE) {
            const int vg = chunk*VT + (t+1)*TV + rr;
            const float* rowp = embB + (size_t)(mkn ? vg : (chunk*VT + (t+1)*TV + w*16))*EMB;
            #pragma unroll
            for (int f = 0; f < 4; ++f) {
                const float4* src = (const float4*)(rowp + f*32 + lhi*8);
                pfa[f] = src[0]; pfb[f] = src[1];
            }
            mk = mkn;
        }

        // ---- QK from registers: S[v=w*16+..][h] ----
        f32x4 s = {0.f,0.f,0.f,0.f};
        #pragma unroll
        for (int f = 0; f < 4; ++f)
            s = __builtin_amdgcn_mfma_f32_16x16x32_bf16(ef[f], qf[f], s, 0, 0, 0);

        // lane holds S[v = w*16 + lhi*4 + r][h = llo]
        f32x4 nn = *(const f32x4*)(&nsq[w*16 + lhi*4]);   // within-wave dep only
        float p[4];
        #pragma unroll
        for (int r = 0; r < 4; ++r)
            p[r] = (nn[r] > 0.f) ? __expf(s[r]*rsqrtf(nn[r]) - 1.f) : 0.f;  // |cos|<=1
        uint32_t u0 = packbf(p[0], p[1]), u1 = packbf(p[2], p[3]);
        Lh += __uint_as_float(u0 << 16) + __uint_as_float(u0 & 0xFFFF0000u)
            + __uint_as_float(u1 << 16) + __uint_as_float(u1 & 0xFFFF0000u);
        {
            unsigned char* pdst = Pbuf + llo*PST + (w*16 + lhi*4)*2;
            *(uint32_t*)(pdst)     = u0;
            *(uint32_t*)(pdst + 4) = u1;
        }

        BAR();   // single barrier: E-writes + P-writes -> PV reads (dbuf guards rest)

        // ---- PV: O[h][e] += P · E  (A=P b128; B=E u16 gathers, proven) ----
        #pragma unroll
        for (int kf = 0; kf < 2; ++kf) {
            // A-frag: lane(llo,lhi) needs P[h=llo][v = kf*32 + lhi*8 + i]
            bf16x8 pa = *(const bf16x8*)(Pbuf + llo*PST + kf*64 + lhi*16);
            #pragma unroll
            for (int et = 0; et < 2; ++et) {
                const unsigned char* base = Ebuf + (2*w + et)*EST + llo*2;
                bf16x8 bb;
                #pragma unroll
                for (int i = 0; i < 8; ++i)
                    bb[i] = *(const short*)(base + (size_t)(kf*32 + lhi*8 + i)*32);
                if (et == 0) acc0 = __builtin_amdgcn_mfma_f32_16x16x32_bf16(pa, bb, acc0, 0, 0, 0);
                else         acc1 = __builtin_amdgcn_mfma_f32_16x16x32_bf16(pa, bb, acc1, 0, 0, 0);
            }
        }
        // no trailing barrier: next tile writes the OTHER E/P buffers
    }

    // ---- epilogue: partial O and partial lsum ----
    float* pout = pacc + (((size_t)b*NCHUNK + chunk)*NH)*EMB;
    #pragma unroll
    for (int r = 0; r < 4; ++r) {
        pout[(lhi*4 + r)*EMB + w*32 + llo]      = acc0[r];
        pout[(lhi*4 + r)*EMB + w*32 + 16 + llo] = acc1[r];
    }
    Lh += __shfl_xor(Lh, 16);
    Lh += __shfl_xor(Lh, 32);
    if (l < 16) lred[w][l] = Lh;
    BAR();
    if (tid < 16)
        lpart[((size_t)b*NCHUNK + chunk)*NH + tid] =
            lred[0][tid] + lred[1][tid] + lred[2][tid] + lred[3][tid];
}

// K6: rc[b,h,e] = sum_chunk pacc / sum_chunk lpart; block 0 also writes the loss
__global__ __launch_bounds__(128) void k6_out(const float* __restrict__ pacc,
                                              const float* __restrict__ lpart,
                                              const float* __restrict__ lossp,
                                              float* __restrict__ out) {
    const int bh = blockIdx.x;
    const int b = bh >> 4, h = bh & 15;
    const int e = threadIdx.x;
    float L = 0.f;
    #pragma unroll
    for (int c = 0; c < NCHUNK; ++c) L += lpart[((size_t)b*NCHUNK + c)*NH + h];
    float acc = 0.f;
    for (int k = 0; k < NCHUNK; ++k)
        acc += pacc[(((size_t)b*NCHUNK + k)*NH + h)*EMB + e];
    out[((size_t)b*NH + h)*EMB + e] = acc / L;
    if (bh == 0 && e < 64) {
        float v = (e < BS) ? lossp[e] : 0.f;
        #pragma unroll
        for (int off = 32; off; off >>= 1) v += __shfl_xor(v, off);
        if (e == 0) out[BS*NH*EMB] = v / (float)BS;
    }
}

extern "C" void kernel_launch(void* const* d_in, const int* in_sizes, int n_in,
                              void* d_out, int out_size, void* d_ws, size_t ws_size,
                              hipStream_t stream) {
    const float* seed = (const float*)d_in[0];
    const float* emb  = (const float*)d_in[1];
    const int*   mask = (const int*)d_in[2];
    const float* wqs  = (const float*)d_in[3];
    float* out = (float*)d_out;

    char* ws = (char*)d_ws;
    float* normq = (float*)(ws + OFF_NORMQ);
    float* lossp = (float*)(ws + OFF_LOSSP);
    float* lpart = (float*)(ws + OFF_LPART);
    float* pacc  = (float*)(ws + OFF_PACC);

    k1_q<<<BS*NH, 128, 0, stream>>>(seed, wqs, normq);
    k2_loss<<<BS, 256, 0, stream>>>(normq, lossp);
    k_fused<<<dim3(NCHUNK, BS), 256, 0, stream>>>(emb, mask, normq, pacc, lpart);
    k6_out<<<BS*NH, 128, 0, stream>>>(pacc, lpart, lossp, out);
}